// Round 1
// baseline (756.097 us; speedup 1.0000x reference)
//
#include <hip/hip_runtime.h>
#include <hip/hip_bf16.h>

// Problem constants
#define NROW 778
#define NPAD 784     // 49*16
#define FDIM 128
#define KHID 256

typedef unsigned short u16;
typedef __attribute__((ext_vector_type(4))) unsigned int u32x4;
typedef __attribute__((ext_vector_type(4))) float f32x4;

__device__ __forceinline__ u16 f2bfu(float x) {
  return __builtin_bit_cast(u16, __float2bfloat16(x));
}

__device__ __forceinline__ void mfma_bf16(f32x4& d, const u32x4& a, const u32x4& b) {
  // D = A(16x32) * B(32x16) + D, bf16 inputs, f32 acc
  asm("v_mfma_f32_16x16x32_bf16 %0, %1, %2, %0" : "+v"(d) : "v"(a), "v"(b));
}

// ---------------- workspace layout (bytes) ----------------
#define WS_A    0u           // a[784][256] f32
#define WS_C    802816u      // c[784][256] f32
#define WS_XI   1605632u     // xi[784][128] f32  (Lq + bq + pos_b2)
#define WS_XJ   2007040u     // xj[784][128] f32  (-(Rk + bk))
#define WS_VJ   2408448u     // vj[784][128] f32  (Lv + bv + pos_b2)
#define WS_S    2809856u     // S[784][128] f32 column sums
#define WS_INV  3211264u     // invS[784][128] f32
#define WS_AGG  3612672u     // agg[784][128] f32
#define WS_W2B  4014080u     // W2 frag-order bf16 [8][8][64][8]
#define WS_C1B  4079616u     // conv1 frag-order bf16 [4][4][64][8]
#define WS_C2B  4096000u     // conv2 frag-order bf16 [8][64][8]
// end 4104192

// ---------------- shared-memory layout for kpass (bytes) ----------------
#define SM_A    0        // sA[16][256] f32                (phase 1)
#define SM_CF   16384    // sCf frag [8][64][8] f32        (phase 1)
#define SM_W2B  32768    // [8][8][64][8] bf16             (phase 1)
#define SM_HID  0        // alias: per-wave hid [8][64][8] bf16  (phase 2)
#define SM_XJ   65536    // sXj[16][128] f32               (phase 2)
#define SM_SP   73728    // pass A: S partial [16][128] f32
#define SM_INVS 73728    // pass B: invS tile [16][128] f32
#define SM_VJ   81920    // pass B: vj tile [16][128] f32
#define SM_C1B  98304    // [4][4][64][8] bf16
#define SM_C2B  114688   // [8][64][8] bf16
#define SM_X    122880   // per-wave x frag [4][64][8] bf16 (8 waves)
#define SM_CB1  155648   // conv1_b f32[256]
#define SM_CB2  156672   // conv2_b f32[128]
#define SM_TOTAL 157184

// ---------------------------------------------------------------
__global__ void kzero(float* S, float* agg) {
  int idx = blockIdx.x * blockDim.x + threadIdx.x;
  if (idx < NPAD * FDIM) { S[idx] = 0.f; agg[idx] = 0.f; }
}

__global__ void kinv(const float* __restrict__ S, float* __restrict__ invS) {
  int idx = blockIdx.x * blockDim.x + threadIdx.x;
  if (idx >= NPAD * FDIM) return;
  int j = idx >> 7;
  invS[idx] = (j < NROW) ? 1.f / S[idx] : 0.f;
}

// Per-row projections: a, c (pos MLP layer 1) and xi, xj, vj
__global__ void kprep_rows(const float* __restrict__ Lf, const float* __restrict__ Rf,
                           const float* __restrict__ lp, const float* __restrict__ rp,
                           const float* __restrict__ W1, const float* __restrict__ b1,
                           const float* __restrict__ b2,
                           const float* __restrict__ Wq, const float* __restrict__ bq,
                           const float* __restrict__ Wv, const float* __restrict__ bv,
                           const float* __restrict__ Wk, const float* __restrict__ bk,
                           float* __restrict__ a, float* __restrict__ c,
                           float* __restrict__ xi, float* __restrict__ xj,
                           float* __restrict__ vj) {
  __shared__ float sl[128], sr[128], slp[128], srp[128];
  const int row = blockIdx.x, t = threadIdx.x;
  if (t < 128) {
    sl[t] = Lf[row * 128 + t]; sr[t] = Rf[row * 128 + t];
    slp[t] = lp[row * 128 + t]; srp[t] = rp[row * 128 + t];
  }
  __syncthreads();
  float aa = 0.f, cc = 0.f;
  for (int k = 0; k < 128; ++k) {
    float w = W1[k * 256 + t];
    aa += slp[k] * w; cc += srp[k] * w;
  }
  a[row * 256 + t] = aa;
  c[row * 256 + t] = b1[t] - cc;
  if (t < 128) {
    float q = 0.f, kk = 0.f, vv = 0.f;
    for (int k = 0; k < 128; ++k) {
      float l = sl[k], r = sr[k];
      q  += l * Wq[k * 128 + t];
      vv += l * Wv[k * 128 + t];
      kk += r * Wk[k * 128 + t];
    }
    xi[row * 128 + t] = q + bq[t] + b2[t];
    xj[row * 128 + t] = -(kk + bk[t]);
    vj[row * 128 + t] = vv + bv[t] + b2[t];
  }
}

// Repack weights into MFMA fragment order (bf16)
__global__ void kprep_frags(const float* __restrict__ W2, const float* __restrict__ c1w,
                            const float* __restrict__ c2w,
                            u16* __restrict__ w2B, u16* __restrict__ c1B,
                            u16* __restrict__ c2B) {
  const int idx0 = blockIdx.x * blockDim.x + threadIdx.x;
  const int nthr = gridDim.x * blockDim.x;
  // w2B[ks][n][lane][e] = W2[ks*32 + (lane>>4)*8 + e][n*16 + (lane&15)]
  for (int idx = idx0; idx < 32768; idx += nthr) {
    int e = idx & 7, ln = (idx >> 3) & 63, n = (idx >> 9) & 7, ks = idx >> 12;
    int k = ks * 32 + ((ln >> 4) << 3) + e;
    int col = n * 16 + (ln & 15);
    w2B[idx] = f2bfu(W2[k * FDIM + col]);
  }
  // c1B[hp][b][lane][e]: block-diag 2-head conv1, K=32
  for (int idx = idx0; idx < 8192; idx += nthr) {
    int e = idx & 7, ln = (idx >> 3) & 63, b = (idx >> 9) & 3, hp = idx >> 11;
    int k = ((ln >> 4) << 3) + e;     // 0..31 channel within head pair
    int col = ln & 15;                // out col within 16-block
    int hb = hp * 2 + (b >> 1);
    float v = ((k >> 4) == (b >> 1)) ? c1w[(hb * 32 + (b & 1) * 16 + col) * 16 + (k & 15)] : 0.f;
    c1B[idx] = f2bfu(v);
  }
  // c2B[h][lane][e]: B[o][d] = conv2_w[h][d][o], K=32
  for (int idx = idx0; idx < 4096; idx += nthr) {
    int e = idx & 7, ln = (idx >> 3) & 63, h = idx >> 9;
    int o = ((ln >> 4) << 3) + e;
    int d = ln & 15;
    c2B[idx] = f2bfu(c2w[(h * 16 + d) * 32 + o]);
  }
}

// ---------------- main pair-tile kernels ----------------
// PASS 0: accumulate S[j][ch] = sum_i exp(sim)
// PASS 1: accumulate agg[i][ch] = sum_j exp(sim)*invS[j][ch]*(rel_raw + vj[j][ch])
template <int PASS>
__global__ __launch_bounds__(512, 2) void kpass(
    const float* __restrict__ ga, const float* __restrict__ gc,
    const float* __restrict__ gxi, const float* __restrict__ gxj,
    const float* __restrict__ gvj, const u16* __restrict__ gw2B,
    const u16* __restrict__ gc1B, const u16* __restrict__ gc2B,
    const float* __restrict__ gcb1, const float* __restrict__ gcb2,
    float* __restrict__ S, const float* __restrict__ invS, float* __restrict__ agg) {
  __shared__ __align__(16) char sm[SM_TOTAL];
  float* sA   = (float*)(sm + SM_A);
  float* sCf  = (float*)(sm + SM_CF);
  u16*   sW2B = (u16*)(sm + SM_W2B);
  u16*   sHid = (u16*)(sm + SM_HID);
  float* sXj  = (float*)(sm + SM_XJ);
  float* sSp  = (float*)(sm + SM_SP);
  float* sInvS= (float*)(sm + SM_INVS);
  float* sVj  = (float*)(sm + SM_VJ);
  u16*   sC1B = (u16*)(sm + SM_C1B);
  u16*   sC2B = (u16*)(sm + SM_C2B);
  u16*   sX   = (u16*)(sm + SM_X);
  float* sCB1 = (float*)(sm + SM_CB1);
  float* sCB2 = (float*)(sm + SM_CB2);

  const int tid = threadIdx.x;
  const int lane = tid & 63;
  const int w = tid >> 6;
  const int jj = lane & 15, kg = lane >> 4;
  const int i0 = blockIdx.x * 16, j0 = blockIdx.y * 16;

  // ---- stage phase 1 ----
  for (int idx = tid; idx < 4096; idx += 512) {  // sA row-major
    int row = idx >> 8;
    int ir = i0 + row; if (ir > NROW - 1) ir = NROW - 1;
    sA[idx] = ga[ir * KHID + (idx & 255)];
  }
  for (int idx = tid; idx < 4096; idx += 512) {  // sCf frag order [ks][lane][e]
    int ks = idx >> 9, ln = (idx >> 3) & 63, e = idx & 7;
    int jr = j0 + (ln & 15); if (jr > NROW - 1) jr = NROW - 1;
    int k = ks * 32 + ((ln >> 4) << 3) + e;
    sCf[idx] = gc[jr * KHID + k];
  }
  {
    const u32x4* g = (const u32x4*)gw2B; u32x4* s = (u32x4*)sW2B;
    for (int idx = tid; idx < 4096; idx += 512) s[idx] = g[idx];
    const u32x4* g1 = (const u32x4*)gc1B; u32x4* s1 = (u32x4*)sC1B;
    for (int idx = tid; idx < 1024; idx += 512) s1[idx] = g1[idx];
    const u32x4* g2 = (const u32x4*)gc2B; u32x4* s2 = (u32x4*)sC2B;
    s2[tid] = g2[tid];  // 512 of them
    if (tid < 256) sCB1[tid] = gcb1[tid];
    else if (tid < 384) sCB2[tid - 256] = gcb2[tid - 256];
  }
  __syncthreads();

  // ---- main GEMM: rel_raw = relu(a+c) @ W2 ----
  f32x4 acc[2][8];
#pragma unroll
  for (int mt = 0; mt < 2; ++mt)
#pragma unroll
    for (int n = 0; n < 8; ++n) acc[mt][n] = f32x4{0.f, 0.f, 0.f, 0.f};

#pragma unroll
  for (int ks = 0; ks < 8; ++ks) {
    const float4 c0 = *(const float4*)&sCf[(ks * 64 + lane) * 8];
    const float4 c1 = *(const float4*)&sCf[(ks * 64 + lane) * 8 + 4];
    const int ko = ks * 32 + kg * 8;
    u32x4 A[2];
#pragma unroll
    for (int mt = 0; mt < 2; ++mt) {
      const float4 a0 = *(const float4*)&sA[(2 * w + mt) * KHID + ko];
      const float4 a1 = *(const float4*)&sA[(2 * w + mt) * KHID + ko + 4];
      float h0 = fmaxf(a0.x + c0.x, 0.f), h1 = fmaxf(a0.y + c0.y, 0.f);
      float h2 = fmaxf(a0.z + c0.z, 0.f), h3 = fmaxf(a0.w + c0.w, 0.f);
      float h4 = fmaxf(a1.x + c1.x, 0.f), h5 = fmaxf(a1.y + c1.y, 0.f);
      float h6 = fmaxf(a1.z + c1.z, 0.f), h7 = fmaxf(a1.w + c1.w, 0.f);
      A[mt] = u32x4{(unsigned)f2bfu(h0) | ((unsigned)f2bfu(h1) << 16),
                    (unsigned)f2bfu(h2) | ((unsigned)f2bfu(h3) << 16),
                    (unsigned)f2bfu(h4) | ((unsigned)f2bfu(h5) << 16),
                    (unsigned)f2bfu(h6) | ((unsigned)f2bfu(h7) << 16)};
    }
#pragma unroll
    for (int n = 0; n < 8; ++n) {
      u32x4 B = ((const u32x4*)sW2B)[(ks * 8 + n) * 64 + lane];
      mfma_bf16(acc[0][n], A[0], B);
      mfma_bf16(acc[1][n], A[1], B);
    }
  }
  __syncthreads();  // sA/sCf/sW2B dead beyond this point (aliased below)

  // ---- stage phase 2 ----
  if (PASS == 0) {
    for (int idx = tid; idx < 2048; idx += 512) sSp[idx] = 0.f;
  } else {
    for (int idx = tid; idx < 2048; idx += 512) {
      int row = idx >> 7, ch = idx & 127;
      int jr = j0 + row;                 // <= 783; invS padded with zeros
      sInvS[idx] = invS[jr * FDIM + ch];
      int jc = jr > NROW - 1 ? NROW - 1 : jr;
      sVj[idx] = gvj[jc * FDIM + ch];
    }
  }
  for (int idx = tid; idx < 2048; idx += 512) {
    int row = idx >> 7, ch = idx & 127;
    int jr = j0 + row; if (jr > NROW - 1) jr = NROW - 1;
    sXj[idx] = gxj[jr * FDIM + ch];
  }
  __syncthreads();

  // ---- per-wave conv + epilogue ----
  u16* myX = sX + w * 2048;    // [4][64][8] bf16, conv1 A-frag order
  u16* myH = sHid + w * 4096;  // [8][64][8] bf16, conv2 A-frag order
#pragma unroll
  for (int mt = 0; mt < 2; ++mt) {
    const int i = i0 + 2 * w + mt;
    const int ic = i > NROW - 1 ? NROW - 1 : i;
    // x = rel_raw + xi[i] + xj[j] -> LDS in conv1 A-frag order
#pragma unroll
    for (int n = 0; n < 8; ++n) {
      const int ch = n * 16 + jj;
      const float xiv = gxi[ic * FDIM + ch];
#pragma unroll
      for (int r = 0; r < 4; ++r) {
        const int prow = kg * 4 + r;
        float xv = acc[mt][n][r] + xiv + sXj[prow * FDIM + ch];
        int idxX = ((ch >> 5) * 512) + (prow + 16 * ((ch >> 3) & 3)) * 8 + (ch & 7);
        myX[idxX] = f2bfu(xv);
      }
    }
    // conv1 (per 2-head group, K=32 block diagonal)
#pragma unroll
    for (int hp = 0; hp < 4; ++hp) {
      u32x4 Ax = ((const u32x4*)myX)[hp * 64 + lane];
#pragma unroll
      for (int b = 0; b < 4; ++b) {
        u32x4 Bw = ((const u32x4*)sC1B)[(hp * 4 + b) * 64 + lane];
        f32x4 hacc = f32x4{0.f, 0.f, 0.f, 0.f};
        mfma_bf16(hacc, Ax, Bw);
        const int och = (hp * 2 + (b >> 1)) * 32 + (b & 1) * 16 + jj;
        const float bias = sCB1[och];
#pragma unroll
        for (int r = 0; r < 4; ++r) {
          const int prow = kg * 4 + r;
          float hv = fmaxf(hacc[r] + bias, 0.f);
          int idxH = ((och >> 5) * 512) + (prow + 16 * ((och >> 3) & 3)) * 8 + (och & 7);
          myH[idxH] = f2bfu(hv);
        }
      }
    }
    // conv2 + softmax-related epilogue, per head
#pragma unroll
    for (int h = 0; h < 8; ++h) {
      u32x4 Ah = ((const u32x4*)myH)[h * 64 + lane];
      u32x4 Bw = ((const u32x4*)sC2B)[h * 64 + lane];
      f32x4 sacc = f32x4{0.f, 0.f, 0.f, 0.f};
      mfma_bf16(sacc, Ah, Bw);
      const float bias = sCB2[h * 16 + jj];
      if (PASS == 0) {
        if (i < NROW) {
#pragma unroll
          for (int r = 0; r < 4; ++r) {
            float e = __expf(sacc[r] + bias);
            atomicAdd(&sSp[(kg * 4 + r) * FDIM + h * 16 + jj], e);
          }
        }
      } else {
        float sum = 0.f;
#pragma unroll
        for (int r = 0; r < 4; ++r) {
          const int prow = kg * 4 + r;
          float e = __expf(sacc[r] + bias);
          float iv = sInvS[prow * FDIM + h * 16 + jj];   // 0 for padded j
          float vv = acc[mt][h][r] + sVj[prow * FDIM + h * 16 + jj];
          sum += e * iv * vv;
        }
        sum += __shfl_xor(sum, 16);
        sum += __shfl_xor(sum, 32);
        if (lane < 16) atomicAdd(&agg[i * FDIM + h * 16 + lane], sum);
      }
    }
  }
  if (PASS == 0) {
    __syncthreads();
    for (int idx = tid; idx < 2048; idx += 512) {
      int row = idx >> 7;
      atomicAdd(&S[(j0 + row) * FDIM + (idx & 127)], sSp[idx]);
    }
  }
}

// y = Lf + agg; out = y + fc2(relu(fc1(LN(y))))
__global__ void kfinal(const float* __restrict__ Lf, const float* __restrict__ agg,
                       const float* __restrict__ g, const float* __restrict__ b,
                       const float* __restrict__ W1, const float* __restrict__ b1,
                       const float* __restrict__ W2, const float* __restrict__ b2,
                       float* __restrict__ out) {
  __shared__ float sY[128], sYn[128], sH[256], sStat[2];
  const int row = blockIdx.x, t = threadIdx.x;
  if (t < 128) sY[t] = Lf[row * 128 + t] + agg[row * 128 + t];
  __syncthreads();
  if (t < 64) {
    float y0 = sY[t], y1 = sY[t + 64];
    float s = y0 + y1, s2 = y0 * y0 + y1 * y1;
#pragma unroll
    for (int off = 32; off; off >>= 1) {
      s += __shfl_down(s, off);
      s2 += __shfl_down(s2, off);
    }
    if (t == 0) {
      float mu = s * (1.f / 128.f);
      float var = s2 * (1.f / 128.f) - mu * mu;
      sStat[0] = mu;
      sStat[1] = rsqrtf(var + 1e-6f);
    }
  }
  __syncthreads();
  if (t < 128) sYn[t] = (sY[t] - sStat[0]) * sStat[1] * g[t] + b[t];
  __syncthreads();
  float ha = b1[t];
  for (int k = 0; k < 128; ++k) ha += sYn[k] * W1[k * 256 + t];
  sH[t] = fmaxf(ha, 0.f);
  __syncthreads();
  if (t < 128) {
    float oa = b2[t];
    for (int k = 0; k < 256; ++k) oa += sH[k] * W2[k * 128 + t];
    out[row * 128 + t] = sY[t] + oa;
  }
}

extern "C" void kernel_launch(void* const* d_in, const int* in_sizes, int n_in,
                              void* d_out, int out_size, void* d_ws, size_t ws_size,
                              hipStream_t stream) {
  const float* Lf  = (const float*)d_in[0];
  const float* Rf  = (const float*)d_in[1];
  const float* lp  = (const float*)d_in[2];
  const float* rp  = (const float*)d_in[3];
  const float* pW1 = (const float*)d_in[4];
  const float* pb1 = (const float*)d_in[5];
  const float* pW2 = (const float*)d_in[6];
  const float* pb2 = (const float*)d_in[7];
  const float* Wq  = (const float*)d_in[8];
  const float* bq  = (const float*)d_in[9];
  const float* Wv  = (const float*)d_in[10];
  const float* bv  = (const float*)d_in[11];
  const float* Wk  = (const float*)d_in[12];
  const float* bk  = (const float*)d_in[13];
  const float* c1w = (const float*)d_in[14];
  const float* c1b = (const float*)d_in[15];
  const float* c2w = (const float*)d_in[16];
  const float* c2b = (const float*)d_in[17];
  const float* lng = (const float*)d_in[18];
  const float* lnb = (const float*)d_in[19];
  const float* fW1 = (const float*)d_in[20];
  const float* fb1 = (const float*)d_in[21];
  const float* fW2 = (const float*)d_in[22];
  const float* fb2 = (const float*)d_in[23];
  float* out = (float*)d_out;
  char* ws = (char*)d_ws;

  float* a    = (float*)(ws + WS_A);
  float* c    = (float*)(ws + WS_C);
  float* xi   = (float*)(ws + WS_XI);
  float* xj   = (float*)(ws + WS_XJ);
  float* vj   = (float*)(ws + WS_VJ);
  float* S    = (float*)(ws + WS_S);
  float* invS = (float*)(ws + WS_INV);
  float* agg  = (float*)(ws + WS_AGG);
  u16* w2B = (u16*)(ws + WS_W2B);
  u16* c1B = (u16*)(ws + WS_C1B);
  u16* c2B = (u16*)(ws + WS_C2B);

  kzero<<<dim3((NPAD * FDIM + 511) / 512), dim3(512), 0, stream>>>(S, agg);
  kprep_rows<<<dim3(NROW), dim3(256), 0, stream>>>(Lf, Rf, lp, rp, pW1, pb1, pb2,
                                                   Wq, bq, Wv, bv, Wk, bk,
                                                   a, c, xi, xj, vj);
  kprep_frags<<<dim3(16), dim3(512), 0, stream>>>(pW2, c1w, c2w, w2B, c1B, c2B);

  kpass<0><<<dim3(49, 49), dim3(512), 0, stream>>>(a, c, xi, xj, vj, w2B, c1B, c2B,
                                                   c1b, c2b, S, invS, agg);
  kinv<<<dim3((NPAD * FDIM + 511) / 512), dim3(512), 0, stream>>>(S, invS);
  kpass<1><<<dim3(49, 49), dim3(512), 0, stream>>>(a, c, xi, xj, vj, w2B, c1B, c2B,
                                                   c1b, c2b, S, invS, agg);
  kfinal<<<dim3(NROW), dim3(256), 0, stream>>>(Lf, agg, lng, lnb, fW1, fb1, fW2, fb2, out);
}